// Round 17
// baseline (453.150 us; speedup 1.0000x reference)
//
#include <hip/hip_runtime.h>
#include <hip/hip_bf16.h>

#define N_NODES 8192
#define F_IN    512
#define DIM     256
#define NCLS    40

typedef __attribute__((ext_vector_type(8))) short bf16x8;
typedef __attribute__((ext_vector_type(4))) float f32x4;

#define MFMA16 __builtin_amdgcn_mfma_f32_16x16x32_bf16

static __device__ __forceinline__ unsigned short f2bf(float x) {
    __hip_bfloat16 h = __float2bfloat16(x);
    return *reinterpret_cast<unsigned short*>(&h);
}
static __device__ __forceinline__ float bf2f(unsigned short u) {
    union { unsigned int u32; float f; } v; v.u32 = ((unsigned int)u) << 16;
    return v.f;
}
static __device__ __forceinline__ void gll16(const void* g, void* l) {
    __builtin_amdgcn_global_load_lds(
        (const __attribute__((address_space(1))) unsigned int*)g,
        (__attribute__((address_space(3))) unsigned int*)l, 16, 0, 0);
}

// ---------------------------------------------------------------------------
// split: fp32 -> (hi, lo) bf16 pair, elementwise. 4 elems/thread.
// ---------------------------------------------------------------------------
__global__ __launch_bounds__(256) void split_kernel(
    const float* __restrict__ X,
    unsigned short* __restrict__ Xh, unsigned short* __restrict__ Xl)
{
    const size_t i = ((size_t)blockIdx.x * 256 + threadIdx.x) * 4;
    float4 v = *(const float4*)&X[i];
    ushort4 h, l;
    h.x = f2bf(v.x); l.x = f2bf(v.x - bf2f(h.x));
    h.y = f2bf(v.y); l.y = f2bf(v.y - bf2f(h.y));
    h.z = f2bf(v.z); l.z = f2bf(v.z - bf2f(h.z));
    h.w = f2bf(v.w); l.w = f2bf(v.w - bf2f(h.w));
    *(ushort4*)&Xh[i] = h;
    *(ushort4*)&Xl[i] = l;
}

// ---------------------------------------------------------------------------
// wtrans body: W fp32 [K,N] -> WT hi/lo bf16 [N,K]. 64x64 LDS transpose.
// ---------------------------------------------------------------------------
static __device__ __forceinline__ void wtrans_body(
    const float* __restrict__ W,
    unsigned short* __restrict__ WTh, unsigned short* __restrict__ WTl,
    int K, int N, int r0, int c0, float (*tile)[65])
{
    const int t = threadIdx.x;
    #pragma unroll
    for (int i = 0; i < 4; ++i) {
        int r = i * 16 + (t >> 4);
        int c = (t & 15) * 4;
        float4 v = *(const float4*)&W[(size_t)(r0 + r) * N + c0 + c];
        tile[r][c] = v.x; tile[r][c + 1] = v.y;
        tile[r][c + 2] = v.z; tile[r][c + 3] = v.w;
    }
    __syncthreads();
    #pragma unroll
    for (int i = 0; i < 4; ++i) {
        int c = i * 16 + (t >> 4);    // N-local
        int r = (t & 15) * 4;         // K-local
        ushort4 h, l;
        float x0 = tile[r][c],     x1 = tile[r + 1][c];
        float x2 = tile[r + 2][c], x3 = tile[r + 3][c];
        h.x = f2bf(x0); l.x = f2bf(x0 - bf2f(h.x));
        h.y = f2bf(x1); l.y = f2bf(x1 - bf2f(h.y));
        h.z = f2bf(x2); l.z = f2bf(x2 - bf2f(h.z));
        h.w = f2bf(x3); l.w = f2bf(x3 - bf2f(h.w));
        *(ushort4*)&WTh[(size_t)(c0 + c) * K + r0 + r] = h;
        *(ushort4*)&WTl[(size_t)(c0 + c) * K + r0 + r] = l;
    }
}

__global__ __launch_bounds__(256) void wtrans_kernel(
    const float* __restrict__ W,
    unsigned short* __restrict__ WTh, unsigned short* __restrict__ WTl,
    int K, int N)
{
    __shared__ float tile[64][65];
    wtrans_body(W, WTh, WTl, K, N, blockIdx.x * 64, blockIdx.y * 64, tile);
}

struct Wt4Args {
    const float* W[4];
    unsigned short* Th[4];
    unsigned short* Tl[4];
};

__global__ __launch_bounds__(256) void wtrans4_kernel(Wt4Args a)
{
    __shared__ float tile[64][65];
    const int z = blockIdx.z;
    wtrans_body(a.W[z], a.Th[z], a.Tl[z], DIM, DIM,
                blockIdx.x * 64, blockIdx.y * 64, tile);
}

// ---------------------------------------------------------------------------
// gemm3 body: 3-term split-bf16 MFMA, BM x 128, BK=32, 4 waves.
// ---------------------------------------------------------------------------
template<int KDIM, int OUTMODE, int BM>
__device__ __forceinline__ void gemm3_body(
    const unsigned short* __restrict__ Ah_, const unsigned short* __restrict__ Al_,
    const unsigned short* __restrict__ Bh_, const unsigned short* __restrict__ Bl_,
    const float* __restrict__ bias,
    void* __restrict__ C0, void* __restrict__ C1,
    int m0, int n0,
    short (*Ah)[32], short (*Al)[32], short (*Bh)[32], short (*Bl)[32])
{
    constexpr int MFRAG = BM / 32;
    constexpr int ACH   = BM / 32;

    const int t = threadIdx.x, lane = t & 63, w = t >> 6;
    const int wm = w >> 1, wn = w & 1;
    const int fr = lane & 15, kb = lane >> 4;

    const unsigned short* asrc[ACH];
    const unsigned short* bsrc[4];
    char* adst[ACH];
    char* bdst[4];
    #pragma unroll
    for (int r = 0; r < ACH; ++r) {
        int c = r * 256 + t;
        int tens = c / (BM * 4), idx = c & (BM * 4 - 1);
        int row = idx >> 2, slot = idx & 3;
        asrc[r] = (tens ? Al_ : Ah_) + (size_t)(m0 + row) * KDIM + slot * 8;
        adst[r] = (char*)(tens ? &Al[0][0] : &Ah[0][0]) + idx * 16;
    }
    #pragma unroll
    for (int r = 0; r < 4; ++r) {
        int c = r * 256 + t;
        int tens = c >> 9, idx = c & 511;
        int row = idx >> 2, slot = idx & 3;
        bsrc[r] = (tens ? Bl_ : Bh_) + (size_t)(n0 + row) * KDIM + slot * 8;
        bdst[r] = (char*)(tens ? &Bl[0][0] : &Bh[0][0]) + idx * 16;
    }

    f32x4 acc[MFRAG][4] = {};

    for (int k0 = 0; k0 < KDIM; k0 += 32) {
        #pragma unroll
        for (int r = 0; r < ACH; ++r) { gll16(asrc[r], adst[r]); asrc[r] += 32; }
        #pragma unroll
        for (int r = 0; r < 4; ++r) { gll16(bsrc[r], bdst[r]); bsrc[r] += 32; }
        __syncthreads();

        bf16x8 ah[MFRAG], al[MFRAG], bh[4], bl[4];
        #pragma unroll
        for (int m = 0; m < MFRAG; ++m) {
            int row = wm * (BM / 2) + m * 16 + fr;
            ah[m] = *(const bf16x8*)&Ah[row][kb * 8];
            al[m] = *(const bf16x8*)&Al[row][kb * 8];
        }
        #pragma unroll
        for (int n = 0; n < 4; ++n) {
            int col = wn * 64 + n * 16 + fr;
            bh[n] = *(const bf16x8*)&Bh[col][kb * 8];
            bl[n] = *(const bf16x8*)&Bl[col][kb * 8];
        }
        #pragma unroll
        for (int m = 0; m < MFRAG; ++m)
            #pragma unroll
            for (int n = 0; n < 4; ++n) {
                acc[m][n] = MFMA16(ah[m], bh[n], acc[m][n], 0, 0, 0);
                acc[m][n] = MFMA16(ah[m], bl[n], acc[m][n], 0, 0, 0);
                acc[m][n] = MFMA16(al[m], bh[n], acc[m][n], 0, 0, 0);
            }
        __syncthreads();
    }

    #pragma unroll
    for (int m = 0; m < MFRAG; ++m)
        #pragma unroll
        for (int e = 0; e < 4; ++e) {
            const int row = m0 + wm * (BM / 2) + m * 16 + kb * 4 + e;
            #pragma unroll
            for (int n = 0; n < 4; ++n) {
                const int col = n0 + wn * 64 + n * 16 + fr;
                float v = acc[m][n][e] + bias[col];
                if (OUTMODE == 0) {
                    ((float*)C0)[(size_t)row * 256 + col] = v;
                } else if (OUTMODE == 1) {
                    ((unsigned short*)C0)[(size_t)row * 256 + col] = f2bf(v);
                } else {
                    unsigned short h = f2bf(v);
                    ((unsigned short*)C0)[(size_t)row * 256 + col] = h;
                    ((unsigned short*)C1)[(size_t)row * 256 + col] =
                        f2bf(v - bf2f(h));
                }
            }
        }
}

template<int KDIM, int OUTMODE, int BM>
__global__ __launch_bounds__(256, (BM == 64) ? 4 : 2) void mfma_gemm3_kernel(
    const unsigned short* __restrict__ Ah_, const unsigned short* __restrict__ Al_,
    const unsigned short* __restrict__ Bh_, const unsigned short* __restrict__ Bl_,
    const float* __restrict__ bias,
    void* __restrict__ C0, void* __restrict__ C1)
{
    __shared__ short Ah[BM][32], Al[BM][32], Bh[128][32], Bl[128][32];
    gemm3_body<KDIM, OUTMODE, BM>(Ah_, Al_, Bh_, Bl_, bias, C0, C1,
                                  blockIdx.y * BM, blockIdx.x * 128,
                                  Ah, Al, Bh, Bl);
}

// ---------------------------------------------------------------------------
// proj4: all four DIM x DIM projections in one launch (z selects weights).
// ---------------------------------------------------------------------------
struct Proj4Args {
    const unsigned short* Bh[4];
    const unsigned short* Bl[4];
    const float* bias[4];
    void* C[4];
};

__global__ __launch_bounds__(256, 2) void proj4_kernel(
    const unsigned short* __restrict__ Ah_, const unsigned short* __restrict__ Al_,
    Proj4Args p)
{
    __shared__ short Ah[128][32], Al[128][32], Bh[128][32], Bl[128][32];
    const int z = blockIdx.z;
    if (z < 3)
        gemm3_body<DIM, 0, 128>(Ah_, Al_, p.Bh[z], p.Bl[z], p.bias[z], p.C[z],
                                nullptr, blockIdx.y * 128, blockIdx.x * 128,
                                Ah, Al, Bh, Bl);
    else
        gemm3_body<DIM, 1, 128>(Ah_, Al_, p.Bh[z], p.Bl[z], p.bias[z], p.C[z],
                                nullptr, blockIdx.y * 128, blockIdx.x * 128,
                                Ah, Al, Bh, Bl);
}

// ---------------------------------------------------------------------------
// LayerNorm + hi/lo bf16 split for Q and K in one launch (blockIdx.y).
// ---------------------------------------------------------------------------
__global__ __launch_bounds__(256) void ln_split2_kernel(
    const float* __restrict__ Qf, const float* __restrict__ Kf,
    unsigned short* __restrict__ Qh, unsigned short* __restrict__ Ql,
    unsigned short* __restrict__ Kh, unsigned short* __restrict__ Kl)
{
    const int row = blockIdx.x;
    const int t = threadIdx.x;
    const float* X = blockIdx.y ? Kf : Qf;
    unsigned short* Hi = blockIdx.y ? Kh : Qh;
    unsigned short* Lo = blockIdx.y ? Kl : Ql;

    float x = X[(size_t)row * DIM + t];

    float s1 = x, s2 = x * x;
    #pragma unroll
    for (int o = 32; o; o >>= 1) {
        s1 += __shfl_xor(s1, o);
        s2 += __shfl_xor(s2, o);
    }
    __shared__ float r1[4], r2[4];
    const int wid = t >> 6;
    if ((t & 63) == 0) { r1[wid] = s1; r2[wid] = s2; }
    __syncthreads();
    const float sum = r1[0] + r1[1] + r1[2] + r1[3];
    const float ssq = r2[0] + r2[1] + r2[2] + r2[3];
    const float mean = sum * (1.0f / DIM);
    const float var  = ssq * (1.0f / DIM) - mean * mean;
    const float y = (x - mean) * rsqrtf(var + 1e-5f);

    const unsigned short h = f2bf(y);
    Hi[(size_t)row * DIM + t] = h;
    Lo[(size_t)row * DIM + t] = f2bf(y - bf2f(h));
}

// ---------------------------------------------------------------------------
// V [8192,256] fp32 -> VT [256,8192] bf16.
// ---------------------------------------------------------------------------
__global__ __launch_bounds__(256) void vtrans_kernel(
    const float* __restrict__ V, unsigned short* __restrict__ VT)
{
    __shared__ float tile[64][65];
    const int r0 = blockIdx.x * 64;
    const int c0 = blockIdx.y * 64;
    const int t = threadIdx.x;
    #pragma unroll
    for (int i = 0; i < 4; ++i) {
        int r = i * 16 + (t >> 4);
        int c = (t & 15) * 4;
        float4 v = *(const float4*)&V[(size_t)(r0 + r) * DIM + c0 + c];
        tile[r][c] = v.x; tile[r][c + 1] = v.y;
        tile[r][c + 2] = v.z; tile[r][c + 3] = v.w;
    }
    __syncthreads();
    #pragma unroll
    for (int i = 0; i < 4; ++i) {
        int c = i * 16 + (t >> 4);
        int r = (t & 15) * 4;
        ushort4 o;
        o.x = f2bf(tile[r][c]);     o.y = f2bf(tile[r + 1][c]);
        o.z = f2bf(tile[r + 2][c]); o.w = f2bf(tile[r + 3][c]);
        *(ushort4*)&VT[(size_t)(c0 + c) * N_NODES + r0 + r] = o;
    }
}

// ---------------------------------------------------------------------------
// qkt: 128x256 tile, 8 waves (512 thr). 2 wm x 4 wn. Per-wave 4x4 frags.
// LDS: one contiguous stage[3][256][32]:
//   stage[0] rows 0..127 = Qh, rows 128..255 = Ql; stage[1]=Kh; stage[2]=Kl.
// Epilogue tile (32KB) aliases stage[1..2] (K data dead after main loop).
// ---------------------------------------------------------------------------
__global__ __launch_bounds__(512, 2) void qkt_kernel(
    const unsigned short* __restrict__ Qh_, const unsigned short* __restrict__ Ql_,
    const unsigned short* __restrict__ Kh_, const unsigned short* __restrict__ Kl_,
    unsigned short* __restrict__ Sb, float2* __restrict__ pstat)
{
    __shared__ short stage[3][256][32];   // 48KB contiguous
    __shared__ float2 ps[4][128];
    __shared__ float gmr[128];

    // 2D-chunked XCD swizzle over (mb 0..63) x (nbp 0..31)
    const int bid = blockIdx.x;           // 0..2047
    const int x   = bid & 7;
    const int i   = bid >> 3;             // 0..255
    const int nps = i >> 6;               // 0..3
    const int j   = i & 63;
    const int mb  = x * 8 + (j & 7);
    const int nbp = nps * 8 + (j >> 3);
    const int m0 = mb * 128, n0 = nbp * 256;
    const int nb0 = nbp * 2;

    const int t = threadIdx.x, lane = t & 63, w = t >> 6;
    const int wm = w >> 2, wn = w & 3;
    const int fr = lane & 15, kb = lane >> 4;

    // staging: 3072 16B chunks, 6 per thread (hoisted pointers)
    const unsigned short* src[6];
    char* dst[6];
    #pragma unroll
    for (int r = 0; r < 6; ++r) {
        int c = r * 512 + t;
        if (c < 1024) {
            int tens = c >> 9, idx = c & 511;
            int row = idx >> 2, slot = idx & 3;
            src[r] = (tens ? Ql_ : Qh_) + (size_t)(m0 + row) * DIM + slot * 8;
            dst[r] = (char*)&stage[0][0][0] + c * 16;
        } else {
            int cb = c - 1024;
            int tens = cb >> 10, idx = cb & 1023;
            int row = idx >> 2, slot = idx & 3;
            src[r] = (tens ? Kl_ : Kh_) + (size_t)(n0 + row) * DIM + slot * 8;
            dst[r] = (char*)&stage[1][0][0] + cb * 16;
        }
    }

    f32x4 acc[4][4] = {};

    for (int k0 = 0; k0 < DIM; k0 += 32) {
        #pragma unroll
        for (int r = 0; r < 6; ++r) { gll16(src[r], dst[r]); src[r] += 32; }
        __syncthreads();

        bf16x8 ah[4], al[4], bh[4], bl[4];
        #pragma unroll
        for (int m = 0; m < 4; ++m) {
            int row = wm * 64 + m * 16 + fr;
            ah[m] = *(const bf16x8*)&stage[0][row][kb * 8];
            al[m] = *(const bf16x8*)&stage[0][128 + row][kb * 8];
        }
        #pragma unroll
        for (int n = 0; n < 4; ++n) {
            int col = wn * 64 + n * 16 + fr;
            bh[n] = *(const bf16x8*)&stage[1][col][kb * 8];
            bl[n] = *(const bf16x8*)&stage[2][col][kb * 8];
        }
        #pragma unroll
        for (int m = 0; m < 4; ++m)
            #pragma unroll
            for (int n = 0; n < 4; ++n) {
                acc[m][n] = MFMA16(ah[m], bh[n], acc[m][n], 0, 0, 0);
                acc[m][n] = MFMA16(ah[m], bl[n], acc[m][n], 0, 0, 0);
                acc[m][n] = MFMA16(al[m], bh[n], acc[m][n], 0, 0, 0);
            }
        __syncthreads();
    }

    // ---- phase A: per-row max over this block's 256 cols
    #pragma unroll
    for (int m = 0; m < 4; ++m)
        #pragma unroll
        for (int e = 0; e < 4; ++e) {
            float mx = acc[m][0][e];
            #pragma unroll
            for (int n = 1; n < 4; ++n) mx = fmaxf(mx, acc[m][n][e]);
            #pragma unroll
            for (int o = 1; o < 16; o <<= 1) mx = fmaxf(mx, __shfl_xor(mx, o));
            if (fr == 0) ps[wn][wm * 64 + m * 16 + kb * 4 + e].x = mx;
        }
    __syncthreads();
    if (t < 128)
        gmr[t] = fmaxf(fmaxf(ps[0][t].x, ps[1][t].x),
                       fmaxf(ps[2][t].x, ps[3][t].x));
    __syncthreads();

    // ---- phase B: two 128-col halves through the stage[1..2] region (32KB)
    unsigned short* tile = (unsigned short*)&stage[1][0][0];   // [128][128]
    #pragma unroll
    for (int hf = 0; hf < 2; ++hf) {
        if ((wn >> 1) == hf) {
            #pragma unroll
            for (int m = 0; m < 4; ++m)
                #pragma unroll
                for (int e = 0; e < 4; ++e) {
                    const int rl = wm * 64 + m * 16 + kb * 4 + e;
                    const float g = gmr[rl];
                    const int key = kb << 1;       // (rl>>2)&3 == kb
                    float se = 0.f;
                    #pragma unroll
                    for (int n = 0; n < 4; ++n) {
                        float ev = __expf(acc[m][n][e] - g);
                        se += ev;
                        const int col = (wn & 1) * 64 + n * 16 + fr; // 0..127
                        tile[rl * 128 + (((col >> 3) ^ key) << 3) + (col & 7)]
                            = f2bf(ev);
                    }
                    #pragma unroll
                    for (int o = 1; o < 16; o <<= 1) se += __shfl_xor(se, o);
                    if (fr == 0) ps[wn][rl].y = se;
                }
        }
        __syncthreads();

        // store tile -> Sb slot for nb = nb0 + hf (2048 chunks, 4/thread)
        const int nb = nb0 + hf;
        const int sbb = (nb >> 4) * 4096 + 2048 + (nb & 15) * 128;
        #pragma unroll
        for (int p = 0; p < 4; ++p) {
            int c = p * 512 + t;
            int r = c >> 4, sl = c & 15;
            int slx = sl ^ (((r >> 2) & 3) << 1);
            *(int4*)&Sb[(size_t)(m0 + r) * 16384 + sbb + sl * 8] =
                *(const int4*)((const char*)tile + (r * 16 + slx) * 16);
        }
        if (t < 128)
            pstat[(size_t)(m0 + t) * 64 + nb] =
                make_float2(gmr[t], ps[2 * hf][t].y + ps[2 * hf + 1][t].y);
        __syncthreads();
    }
}

// ---------------------------------------------------------------------------
// av_mfma: producer/consumer split, 512 threads.
// Waves 0-3: ZA partials = (factor * Sb) @ VT^T (MFMA + staging).
// Waves 4-7: in-place fp32 attn expansion of the step being computed.
// ---------------------------------------------------------------------------
__global__ __launch_bounds__(512, 2) void av_mfma_kernel(
    const unsigned short* __restrict__ Sb, const float2* __restrict__ pstat,
    const unsigned short* __restrict__ VT, float* __restrict__ attn,
    float* __restrict__ P0, float* __restrict__ P1,
    float* __restrict__ P2, float* __restrict__ P3)
{
    __shared__ unsigned short As[2][64][128];
    __shared__ float facsT[16][64];

    const int bid = blockIdx.x;
    const int x = bid & 7, i = bid >> 3;
    const int ks = i >> 4;
    const int rb = (i & 15) * 8 + x;
    const int r0 = rb * 64, kbase = ks * 2048, cb0 = ks * 16;
    const int t = threadIdx.x;
    const bool producer = (t < 256);
    const int tp = t & 255;
    const int lane = tp & 63, w = tp >> 6;
    const int fr = lane & 15, kb = lane >> 4;

    {
        const int row = t >> 3;
        const int sub = t & 7;
        const float2* pp = pstat + (size_t)(r0 + row) * 64 + sub * 8;
        float m = -3.0e38f, s = 0.f;
        #pragma unroll
        for (int jj = 0; jj < 8; ++jj) {
            float2 v = pp[jj];
            float nm = fmaxf(m, v.x);
            s = s * __expf(m - nm) + v.y * __expf(v.x - nm);
            m = nm;
        }
        #pragma unroll
        for (int o = 1; o < 8; o <<= 1) {
            float om = __shfl_xor(m, o);
            float os = __shfl_xor(s, o);
            float nm = fmaxf(m, om);
            s = s * __expf(m - nm) + os * __expf(om - nm);
            m = nm;
        }
        const float inv = 1.0f / s;
        #pragma unroll
        for (int jj = 0; jj < 2; ++jj) {
            int cb = sub * 2 + jj;
            float2 v = pstat[(size_t)(r0 + row) * 64 + cb0 + cb];
            facsT[cb][row] = __expf(v.x - m) * inv;
        }
    }

    const unsigned short* vb[4];
    #pragma unroll
    for (int n = 0; n < 4; ++n)
        vb[n] = VT + (size_t)(w * 64 + n * 16 + fr) * N_NODES + kbase + kb * 8;

    const unsigned short* ssrc[4];
    char* sdst[4];
    #pragma unroll
    for (int p = 0; p < 4; ++p) {
        int c = p * 256 + tp;
        int rr = c >> 4, sl = c & 15;
        int slp = sl ^ (rr & 7);
        ssrc[p] = Sb + (size_t)(r0 + rr) * 16384 + ks * 4096 + 2048 + slp * 8;
        sdst[p] = (char*)&As[0][0][0] + c * 16;
    }

    #define STAGE(BUF_) do {                                                  \
        _Pragma("unroll")                                                     \
        for (int p = 0; p < 4; ++p) {                                         \
            gll16(ssrc[p], sdst[p] + (BUF_) * 16384);                         \
            ssrc[p] += 128;                                                   \
        } } while (0)

    f32x4 acc[4][4] = {};
    const f32x4 z4 = {0.f, 0.f, 0.f, 0.f};

    if (producer) STAGE(0);
    __syncthreads();

    for (int s = 0; s < 16; ++s) {
        const int b = s & 1;
        const char* abase = (const char*)&As[b][0][0];

        if (producer) {
            if (s + 1 < 16) STAGE(b ^ 1);

            bf16x8 bb[4][4];
            #pragma unroll
            for (int ksl = 0; ksl < 4; ++ksl)
                #pragma unroll
                for (int n = 0; n < 4; ++n)
                    bb[ksl][n] = *(const bf16x8*)(vb[n] + s * 128 + ksl * 32);

            #pragma unroll
            for (int m = 0; m < 4; ++m) {
                f32x4 sacc[4];
                {
                    bf16x8 a = *(const bf16x8*)(abase + (m * 16 + fr) * 256 +
                                                ((kb ^ (fr & 7)) * 16));
                    #pragma unroll
                    for (int n = 0; n < 4; ++n)
                        sacc[n] = MFMA16(a, bb[0][n], z4, 0, 0, 0);
                }
                #pragma unroll
                for (int ksl = 1; ksl < 4; ++ksl) {
                    bf16x8 a = *(const bf16x8*)(abase + (m * 16 + fr) * 256 +
                                                (((ksl * 4 + kb) ^ (fr & 7)) * 16));
                    #pragma unroll
                    for (int n = 0; n < 4; ++n)
                        sacc[n] = MFMA16(a, bb[ksl][n], sacc[n], 0, 0, 0);
                }
                f32x4 fac = *(const f32x4*)&facsT[s][m * 16 + kb * 4];
                #pragma unroll
                for (int n = 0; n < 4; ++n)
                    acc[m][n] += fac * sacc[n];
            }
        } else {
            #pragma unroll
            for (int p = 0; p < 4; ++p) {
                int ci = p * 256 + tp;
                int rr = ci >> 4, g = ci & 15;
                const float fac = facsT[s][rr];
                int4 v = *(const int4*)(abase + (rr * 16 + (g ^ (rr & 7))) * 16);
                float* dst = attn + (size_t)(r0 + rr) * N_NODES +
                             kbase + s * 128 + g * 8;
                float4 o0, o1;
                o0.x = bf2f((unsigned short)(v.x & 0xffff)) * fac;
                o0.y = bf2f((unsigned short)((unsigned)v.x >> 16)) * fac;
                o0.z = bf2f((unsigned short)(v.y & 0xffff)) * fac;
                o0.w = bf2f((unsigned short)((unsigned)v.y >> 16)) * fac;
                o1.x = bf2f((unsigned short)(v.z & 0xffff)) * fac;
                o1.y = bf2f((unsigned short)((unsigned)v.z >> 16)) * fac;
                o1.z = bf2f((unsigned short)(v.w & 0xffff)) * fac;
                o1.w = bf2f((unsigned short)((unsigned)v.w >> 16)) * fac;
                *(float4*)dst       = o0;
                *(float4*)(dst + 4) = o1;
            }
        }
        __syncthreads();
    }
    #undef STAGE

    if (producer) {
        float* P = (ks == 0) ? P0 : (ks == 1) ? P1 : (ks == 2) ? P2 : P3;
        #pragma unroll
        for (int m = 0; m < 4; ++m)
            #pragma unroll
            for (int e = 0; e < 4; ++e) {
                int row = r0 + m * 16 + kb * 4 + e;
                #pragma unroll
                for (int n = 0; n < 4; ++n)
                    P[(size_t)row * DIM + w * 64 + n * 16 + fr] = acc[m][n][e];
            }
    }
}

// ---------------------------------------------------------------------------
// SpMM: one 64-lane wave per node, lane holds 4 features (ushort4 loads).
// ---------------------------------------------------------------------------
__global__ __launch_bounds__(256) void spmm_kernel(
    const unsigned short* __restrict__ Hb, const int* __restrict__ erow,
    const int* __restrict__ ecol, const float* __restrict__ ew,
    float* __restrict__ out, int E)
{
    const int node = blockIdx.x * 4 + (threadIdx.x >> 6);
    const int lane = threadIdx.x & 63;

    int lo = 0, hi = E;
    while (lo < hi) { int mid = (lo + hi) >> 1; if (erow[mid] < node) lo = mid + 1; else hi = mid; }
    const int beg = lo;
    hi = E;
    while (lo < hi) { int mid = (lo + hi) >> 1; if (erow[mid] < node + 1) lo = mid + 1; else hi = mid; }
    const int end = lo;

    float4 acc = make_float4(0.f, 0.f, 0.f, 0.f);
    for (int e = beg; e < end; ++e) {
        const int col = ecol[e];
        const float wgt = ew[e];
        ushort4 h = *(const ushort4*)&Hb[(size_t)col * DIM + lane * 4];
        acc.x += wgt * bf2f(h.x);
        acc.y += wgt * bf2f(h.y);
        acc.z += wgt * bf2f(h.z);
        acc.w += wgt * bf2f(h.w);
    }
    *(float4*)&out[(size_t)node * DIM + lane * 4] = acc;
}

// ---------------------------------------------------------------------------
// Y = (0.5*(P0+P1+P2+P3) + 0.5*GNN) @ Wc + bc
// ---------------------------------------------------------------------------
__global__ __launch_bounds__(256) void blend_cls_kernel(
    const float* __restrict__ p0, const float* __restrict__ p1,
    const float* __restrict__ p2, const float* __restrict__ p3,
    const float* __restrict__ gnn,
    const float* __restrict__ Wc, const float* __restrict__ bc,
    float* __restrict__ Y)
{
    const int row = blockIdx.x;
    const int t = threadIdx.x;
    __shared__ float z[DIM];
    __shared__ float part[4][NCLS];

    const size_t i = (size_t)row * DIM + t;
    z[t] = 0.5f * (p0[i] + p1[i] + p2[i] + p3[i] + gnn[i]);
    __syncthreads();

    if (t < 160) {
        const int c = t % NCLS, q = t / NCLS;
        float acc = 0.0f;
        #pragma unroll 4
        for (int d = q * 64; d < q * 64 + 64; ++d)
            acc += z[d] * Wc[d * NCLS + c];
        part[q][c] = acc;
    }
    __syncthreads();
    if (t < NCLS)
        Y[(size_t)row * NCLS + t] =
            part[0][t] + part[1][t] + part[2][t] + part[3][t] + bc[t];
}

// ---------------------------------------------------------------------------
extern "C" void kernel_launch(void* const* d_in, const int* in_sizes, int n_in,
                              void* d_out, int out_size, void* d_ws, size_t ws_size,
                              hipStream_t stream)
{
    const float* X     = (const float*)d_in[0];
    const int*   erow  = (const int*)d_in[1];
    const int*   ecol  = (const int*)d_in[2];
    const float* ew    = (const float*)d_in[3];
    const float* W_emb = (const float*)d_in[4];
    const float* b_emb = (const float*)d_in[5];
    const float* W_q   = (const float*)d_in[6];
    const float* b_q   = (const float*)d_in[7];
    const float* W_k   = (const float*)d_in[8];
    const float* b_k   = (const float*)d_in[9];
    const float* W_v   = (const float*)d_in[10];
    const float* b_v   = (const float*)d_in[11];
    const float* W_g   = (const float*)d_in[12];
    const float* b_g   = (const float*)d_in[13];
    const float* W_c   = (const float*)d_in[14];
    const float* b_c   = (const float*)d_in[15];
    const int E = in_sizes[1];

    float* Y    = (float*)d_out;
    float* Sc   = Y + (size_t)N_NODES * NCLS;
    unsigned short* Sb = (unsigned short*)Sc;

    const size_t ND = (size_t)N_NODES * DIM;
    float* R0 = (float*)d_ws;
    float* R1 = R0 + ND;
    float* R2 = R1 + ND;
    float* R3 = R2 + ND;
    float* R4 = R3 + ND;
    float* R5 = R4 + ND;
    float* R6 = R5 + ND;

    unsigned short* Xh = (unsigned short*)R0;
    unsigned short* Xl = (unsigned short*)R1;
    unsigned short* Wt = (unsigned short*)R2;
    unsigned short* WembTh = Wt;
    unsigned short* WembTl = Wt + 256 * 512;
    unsigned short* WqTh = WembTl + 256 * 512;
    unsigned short* WqTl = WqTh + 256 * 256;
    unsigned short* WkTh = WqTl + 256 * 256;
    unsigned short* WkTl = WkTh + 256 * 256;
    unsigned short* WvTh = WkTl + 256 * 256;
    unsigned short* WvTl = WvTh + 256 * 256;
    unsigned short* WgTh = WvTl + 256 * 256;
    unsigned short* WgTl = WgTh + 256 * 256;
    unsigned short* Z0h = (unsigned short*)R3;
    unsigned short* Z0l = Z0h + ND;
    float* Qf = R4;
    float* Kf = R5;
    float* Vf = R6;
    unsigned short* Hb = (unsigned short*)R0;
    unsigned short* Qh = (unsigned short*)R1;
    unsigned short* Ql = Qh + ND;
    unsigned short* Kh = (unsigned short*)R2;
    unsigned short* Kl = Kh + ND;
    unsigned short* VT = (unsigned short*)(R0 + ND / 2);
    float2* pstat = (float2*)R4;
    float* P0 = R6;
    float* P1 = R3;
    float* P2 = R5;
    float* P3 = R1;
    float* GNN = R2;

    // 1. X -> hi/lo bf16
    split_kernel<<<(N_NODES * F_IN) / 1024, 256, 0, stream>>>(X, Xh, Xl);

    // 2. weight transposes
    wtrans_kernel<<<dim3(F_IN / 64, DIM / 64), 256, 0, stream>>>(
        W_emb, WembTh, WembTl, F_IN, DIM);
    Wt4Args wa;
    wa.W[0] = W_q; wa.Th[0] = WqTh; wa.Tl[0] = WqTl;
    wa.W[1] = W_k; wa.Th[1] = WkTh; wa.Tl[1] = WkTl;
    wa.W[2] = W_v; wa.Th[2] = WvTh; wa.Tl[2] = WvTl;
    wa.W[3] = W_g; wa.Th[3] = WgTh; wa.Tl[3] = WgTl;
    wtrans4_kernel<<<dim3(DIM / 64, DIM / 64, 4), 256, 0, stream>>>(wa);

    // 3. Z0 = X @ W_emb + b
    mfma_gemm3_kernel<F_IN, 2, 64><<<dim3(2, N_NODES / 64), 256, 0, stream>>>(
        Xh, Xl, WembTh, WembTl, b_emb, Z0h, Z0l);

    // 4. projections
    Proj4Args pa;
    pa.Bh[0] = WqTh; pa.Bl[0] = WqTl; pa.bias[0] = b_q; pa.C[0] = Qf;
    pa.Bh[1] = WkTh; pa.Bl[1] = WkTl; pa.bias[1] = b_k; pa.C[1] = Kf;
    pa.Bh[2] = WvTh; pa.Bl[2] = WvTl; pa.bias[2] = b_v; pa.C[2] = Vf;
    pa.Bh[3] = WgTh; pa.Bl[3] = WgTl; pa.bias[3] = b_g; pa.C[3] = Hb;
    proj4_kernel<<<dim3(2, N_NODES / 128, 4), 256, 0, stream>>>(Z0h, Z0l, pa);

    // 5. LN + split
    ln_split2_kernel<<<dim3(N_NODES, 2), 256, 0, stream>>>(
        Qf, Kf, Qh, Ql, Kh, Kl);

    // 6. V -> VT
    vtrans_kernel<<<dim3(N_NODES / 64, DIM / 64), 256, 0, stream>>>(Vf, VT);

    // 7. Sb + pstat (wide 128x256 tiles, 512 threads)
    qkt_kernel<<<2048, 512, 0, stream>>>(Qh, Ql, Kh, Kl, Sb, pstat);

    // 8. ZA partials + factors + in-place attn expansion
    av_mfma_kernel<<<512, 512, 0, stream>>>(
        Sb, pstat, VT, Sc, P0, P1, P2, P3);

    // 9. GNN branch
    spmm_kernel<<<N_NODES / 4, 256, 0, stream>>>(Hb, erow, ecol, ew, GNN, E);

    // 10. blend + classifier
    blend_cls_kernel<<<N_NODES, 256, 0, stream>>>(
        P0, P1, P2, P3, GNN, W_c, b_c, Y);
}

// Round 18
// 397.204 us; speedup vs baseline: 1.1408x; 1.1408x over previous
//
#include <hip/hip_runtime.h>
#include <hip/hip_bf16.h>

#define N_NODES 8192
#define F_IN    512
#define DIM     256
#define NCLS    40

typedef __attribute__((ext_vector_type(8))) short bf16x8;
typedef __attribute__((ext_vector_type(4))) float f32x4;

#define MFMA16 __builtin_amdgcn_mfma_f32_16x16x32_bf16

static __device__ __forceinline__ unsigned short f2bf(float x) {
    __hip_bfloat16 h = __float2bfloat16(x);
    return *reinterpret_cast<unsigned short*>(&h);
}
static __device__ __forceinline__ float bf2f(unsigned short u) {
    union { unsigned int u32; float f; } v; v.u32 = ((unsigned int)u) << 16;
    return v.f;
}
static __device__ __forceinline__ void gll16(const void* g, void* l) {
    __builtin_amdgcn_global_load_lds(
        (const __attribute__((address_space(1))) unsigned int*)g,
        (__attribute__((address_space(3))) unsigned int*)l, 16, 0, 0);
}

// ---------------------------------------------------------------------------
// split: fp32 -> (hi, lo) bf16 pair, elementwise. 4 elems/thread.
// ---------------------------------------------------------------------------
__global__ __launch_bounds__(256) void split_kernel(
    const float* __restrict__ X,
    unsigned short* __restrict__ Xh, unsigned short* __restrict__ Xl)
{
    const size_t i = ((size_t)blockIdx.x * 256 + threadIdx.x) * 4;
    float4 v = *(const float4*)&X[i];
    ushort4 h, l;
    h.x = f2bf(v.x); l.x = f2bf(v.x - bf2f(h.x));
    h.y = f2bf(v.y); l.y = f2bf(v.y - bf2f(h.y));
    h.z = f2bf(v.z); l.z = f2bf(v.z - bf2f(h.z));
    h.w = f2bf(v.w); l.w = f2bf(v.w - bf2f(h.w));
    *(ushort4*)&Xh[i] = h;
    *(ushort4*)&Xl[i] = l;
}

// ---------------------------------------------------------------------------
// wtrans body: W fp32 [K,N] -> WT hi/lo bf16 [N,K]. 64x64 LDS transpose.
// ---------------------------------------------------------------------------
static __device__ __forceinline__ void wtrans_body(
    const float* __restrict__ W,
    unsigned short* __restrict__ WTh, unsigned short* __restrict__ WTl,
    int K, int N, int r0, int c0, float (*tile)[65])
{
    const int t = threadIdx.x;
    #pragma unroll
    for (int i = 0; i < 4; ++i) {
        int r = i * 16 + (t >> 4);
        int c = (t & 15) * 4;
        float4 v = *(const float4*)&W[(size_t)(r0 + r) * N + c0 + c];
        tile[r][c] = v.x; tile[r][c + 1] = v.y;
        tile[r][c + 2] = v.z; tile[r][c + 3] = v.w;
    }
    __syncthreads();
    #pragma unroll
    for (int i = 0; i < 4; ++i) {
        int c = i * 16 + (t >> 4);    // N-local
        int r = (t & 15) * 4;         // K-local
        ushort4 h, l;
        float x0 = tile[r][c],     x1 = tile[r + 1][c];
        float x2 = tile[r + 2][c], x3 = tile[r + 3][c];
        h.x = f2bf(x0); l.x = f2bf(x0 - bf2f(h.x));
        h.y = f2bf(x1); l.y = f2bf(x1 - bf2f(h.y));
        h.z = f2bf(x2); l.z = f2bf(x2 - bf2f(h.z));
        h.w = f2bf(x3); l.w = f2bf(x3 - bf2f(h.w));
        *(ushort4*)&WTh[(size_t)(c0 + c) * K + r0 + r] = h;
        *(ushort4*)&WTl[(size_t)(c0 + c) * K + r0 + r] = l;
    }
}

__global__ __launch_bounds__(256) void wtrans_kernel(
    const float* __restrict__ W,
    unsigned short* __restrict__ WTh, unsigned short* __restrict__ WTl,
    int K, int N)
{
    __shared__ float tile[64][65];
    wtrans_body(W, WTh, WTl, K, N, blockIdx.x * 64, blockIdx.y * 64, tile);
}

struct Wt4Args {
    const float* W[4];
    unsigned short* Th[4];
    unsigned short* Tl[4];
};

__global__ __launch_bounds__(256) void wtrans4_kernel(Wt4Args a)
{
    __shared__ float tile[64][65];
    const int z = blockIdx.z;
    wtrans_body(a.W[z], a.Th[z], a.Tl[z], DIM, DIM,
                blockIdx.x * 64, blockIdx.y * 64, tile);
}

// ---------------------------------------------------------------------------
// gemm3 body: 3-term split-bf16 MFMA, BM x 128, BK=32, 4 waves.
// ---------------------------------------------------------------------------
template<int KDIM, int OUTMODE, int BM>
__device__ __forceinline__ void gemm3_body(
    const unsigned short* __restrict__ Ah_, const unsigned short* __restrict__ Al_,
    const unsigned short* __restrict__ Bh_, const unsigned short* __restrict__ Bl_,
    const float* __restrict__ bias,
    void* __restrict__ C0, void* __restrict__ C1,
    int m0, int n0,
    short (*Ah)[32], short (*Al)[32], short (*Bh)[32], short (*Bl)[32])
{
    constexpr int MFRAG = BM / 32;
    constexpr int ACH   = BM / 32;

    const int t = threadIdx.x, lane = t & 63, w = t >> 6;
    const int wm = w >> 1, wn = w & 1;
    const int fr = lane & 15, kb = lane >> 4;

    const unsigned short* asrc[ACH];
    const unsigned short* bsrc[4];
    char* adst[ACH];
    char* bdst[4];
    #pragma unroll
    for (int r = 0; r < ACH; ++r) {
        int c = r * 256 + t;
        int tens = c / (BM * 4), idx = c & (BM * 4 - 1);
        int row = idx >> 2, slot = idx & 3;
        asrc[r] = (tens ? Al_ : Ah_) + (size_t)(m0 + row) * KDIM + slot * 8;
        adst[r] = (char*)(tens ? &Al[0][0] : &Ah[0][0]) + idx * 16;
    }
    #pragma unroll
    for (int r = 0; r < 4; ++r) {
        int c = r * 256 + t;
        int tens = c >> 9, idx = c & 511;
        int row = idx >> 2, slot = idx & 3;
        bsrc[r] = (tens ? Bl_ : Bh_) + (size_t)(n0 + row) * KDIM + slot * 8;
        bdst[r] = (char*)(tens ? &Bl[0][0] : &Bh[0][0]) + idx * 16;
    }

    f32x4 acc[MFRAG][4] = {};

    for (int k0 = 0; k0 < KDIM; k0 += 32) {
        #pragma unroll
        for (int r = 0; r < ACH; ++r) { gll16(asrc[r], adst[r]); asrc[r] += 32; }
        #pragma unroll
        for (int r = 0; r < 4; ++r) { gll16(bsrc[r], bdst[r]); bsrc[r] += 32; }
        __syncthreads();

        bf16x8 ah[MFRAG], al[MFRAG], bh[4], bl[4];
        #pragma unroll
        for (int m = 0; m < MFRAG; ++m) {
            int row = wm * (BM / 2) + m * 16 + fr;
            ah[m] = *(const bf16x8*)&Ah[row][kb * 8];
            al[m] = *(const bf16x8*)&Al[row][kb * 8];
        }
        #pragma unroll
        for (int n = 0; n < 4; ++n) {
            int col = wn * 64 + n * 16 + fr;
            bh[n] = *(const bf16x8*)&Bh[col][kb * 8];
            bl[n] = *(const bf16x8*)&Bl[col][kb * 8];
        }
        #pragma unroll
        for (int m = 0; m < MFRAG; ++m)
            #pragma unroll
            for (int n = 0; n < 4; ++n) {
                acc[m][n] = MFMA16(ah[m], bh[n], acc[m][n], 0, 0, 0);
                acc[m][n] = MFMA16(ah[m], bl[n], acc[m][n], 0, 0, 0);
                acc[m][n] = MFMA16(al[m], bh[n], acc[m][n], 0, 0, 0);
            }
        __syncthreads();
    }

    #pragma unroll
    for (int m = 0; m < MFRAG; ++m)
        #pragma unroll
        for (int e = 0; e < 4; ++e) {
            const int row = m0 + wm * (BM / 2) + m * 16 + kb * 4 + e;
            #pragma unroll
            for (int n = 0; n < 4; ++n) {
                const int col = n0 + wn * 64 + n * 16 + fr;
                float v = acc[m][n][e] + bias[col];
                if (OUTMODE == 0) {
                    ((float*)C0)[(size_t)row * 256 + col] = v;
                } else if (OUTMODE == 1) {
                    ((unsigned short*)C0)[(size_t)row * 256 + col] = f2bf(v);
                } else {
                    unsigned short h = f2bf(v);
                    ((unsigned short*)C0)[(size_t)row * 256 + col] = h;
                    ((unsigned short*)C1)[(size_t)row * 256 + col] =
                        f2bf(v - bf2f(h));
                }
            }
        }
}

template<int KDIM, int OUTMODE, int BM>
__global__ __launch_bounds__(256, (BM == 64) ? 4 : 2) void mfma_gemm3_kernel(
    const unsigned short* __restrict__ Ah_, const unsigned short* __restrict__ Al_,
    const unsigned short* __restrict__ Bh_, const unsigned short* __restrict__ Bl_,
    const float* __restrict__ bias,
    void* __restrict__ C0, void* __restrict__ C1)
{
    __shared__ short Ah[BM][32], Al[BM][32], Bh[128][32], Bl[128][32];
    gemm3_body<KDIM, OUTMODE, BM>(Ah_, Al_, Bh_, Bl_, bias, C0, C1,
                                  blockIdx.y * BM, blockIdx.x * 128,
                                  Ah, Al, Bh, Bl);
}

// ---------------------------------------------------------------------------
// proj4: all four DIM x DIM projections in one launch (z selects weights).
// ---------------------------------------------------------------------------
struct Proj4Args {
    const unsigned short* Bh[4];
    const unsigned short* Bl[4];
    const float* bias[4];
    void* C[4];
};

__global__ __launch_bounds__(256, 2) void proj4_kernel(
    const unsigned short* __restrict__ Ah_, const unsigned short* __restrict__ Al_,
    Proj4Args p)
{
    __shared__ short Ah[128][32], Al[128][32], Bh[128][32], Bl[128][32];
    const int z = blockIdx.z;
    if (z < 3)
        gemm3_body<DIM, 0, 128>(Ah_, Al_, p.Bh[z], p.Bl[z], p.bias[z], p.C[z],
                                nullptr, blockIdx.y * 128, blockIdx.x * 128,
                                Ah, Al, Bh, Bl);
    else
        gemm3_body<DIM, 1, 128>(Ah_, Al_, p.Bh[z], p.Bl[z], p.bias[z], p.C[z],
                                nullptr, blockIdx.y * 128, blockIdx.x * 128,
                                Ah, Al, Bh, Bl);
}

// ---------------------------------------------------------------------------
// LayerNorm + hi/lo bf16 split for Q and K in one launch (blockIdx.y).
// ---------------------------------------------------------------------------
__global__ __launch_bounds__(256) void ln_split2_kernel(
    const float* __restrict__ Qf, const float* __restrict__ Kf,
    unsigned short* __restrict__ Qh, unsigned short* __restrict__ Ql,
    unsigned short* __restrict__ Kh, unsigned short* __restrict__ Kl)
{
    const int row = blockIdx.x;
    const int t = threadIdx.x;
    const float* X = blockIdx.y ? Kf : Qf;
    unsigned short* Hi = blockIdx.y ? Kh : Qh;
    unsigned short* Lo = blockIdx.y ? Kl : Ql;

    float x = X[(size_t)row * DIM + t];

    float s1 = x, s2 = x * x;
    #pragma unroll
    for (int o = 32; o; o >>= 1) {
        s1 += __shfl_xor(s1, o);
        s2 += __shfl_xor(s2, o);
    }
    __shared__ float r1[4], r2[4];
    const int wid = t >> 6;
    if ((t & 63) == 0) { r1[wid] = s1; r2[wid] = s2; }
    __syncthreads();
    const float sum = r1[0] + r1[1] + r1[2] + r1[3];
    const float ssq = r2[0] + r2[1] + r2[2] + r2[3];
    const float mean = sum * (1.0f / DIM);
    const float var  = ssq * (1.0f / DIM) - mean * mean;
    const float y = (x - mean) * rsqrtf(var + 1e-5f);

    const unsigned short h = f2bf(y);
    Hi[(size_t)row * DIM + t] = h;
    Lo[(size_t)row * DIM + t] = f2bf(y - bf2f(h));
}

// ---------------------------------------------------------------------------
// V [8192,256] fp32 -> VT [256,8192] bf16.
// ---------------------------------------------------------------------------
__global__ __launch_bounds__(256) void vtrans_kernel(
    const float* __restrict__ V, unsigned short* __restrict__ VT)
{
    __shared__ float tile[64][65];
    const int r0 = blockIdx.x * 64;
    const int c0 = blockIdx.y * 64;
    const int t = threadIdx.x;
    #pragma unroll
    for (int i = 0; i < 4; ++i) {
        int r = i * 16 + (t >> 4);
        int c = (t & 15) * 4;
        float4 v = *(const float4*)&V[(size_t)(r0 + r) * DIM + c0 + c];
        tile[r][c] = v.x; tile[r][c + 1] = v.y;
        tile[r][c + 2] = v.z; tile[r][c + 3] = v.w;
    }
    __syncthreads();
    #pragma unroll
    for (int i = 0; i < 4; ++i) {
        int c = i * 16 + (t >> 4);
        int r = (t & 15) * 4;
        ushort4 o;
        o.x = f2bf(tile[r][c]);     o.y = f2bf(tile[r + 1][c]);
        o.z = f2bf(tile[r + 2][c]); o.w = f2bf(tile[r + 3][c]);
        *(ushort4*)&VT[(size_t)(c0 + c) * N_NODES + r0 + r] = o;
    }
}

// ---------------------------------------------------------------------------
// scores = Q @ K^T (split-bf16). 128x128 tile, 4 waves (the verified config).
// Sb = bf16 exp(s-m_blk) packed into the SECOND HALF of each k-slice's fp32
// target range within the attn row slot.
// ---------------------------------------------------------------------------
__global__ __launch_bounds__(256, 4) void qkt_kernel(
    const unsigned short* __restrict__ Qh, const unsigned short* __restrict__ Ql,
    const unsigned short* __restrict__ Kh, const unsigned short* __restrict__ Kl,
    unsigned short* __restrict__ Sb, float2* __restrict__ pstat)
{
    __shared__ short stage[4][128][32];   // Ah/Al/Bh/Bl; reused as bf16 out-tile
    __shared__ float2 ps[2][128];
    __shared__ float gmr[128];

    const int bid = blockIdx.x;
    const int x   = bid & 7;
    const int i   = bid >> 3;
    const int nbs = i >> 6;
    const int j   = i & 63;
    const int mb  = x * 8 + (j & 7);
    const int nb  = nbs * 8 + (j >> 3);
    const int m0 = mb * 128, n0 = nb * 128;
    const int sbbase = (nb >> 4) * 4096 + 2048 + (nb & 15) * 128;  // ushorts

    const int t = threadIdx.x, lane = t & 63, w = t >> 6;
    const int wm = w >> 1, wn = w & 1;
    const int fr = lane & 15, kb = lane >> 4;

    const unsigned short* qsrc[2][2];
    const unsigned short* ksrc[2][2];
    char* qdst[2][2];
    char* kdst[2][2];
    #pragma unroll
    for (int r = 0; r < 2; ++r) {
        int c = r * 256 + t;
        int row = c >> 2, slot = c & 3;
        size_t ga = (size_t)(m0 + row) * DIM + slot * 8;
        size_t gb = (size_t)(n0 + row) * DIM + slot * 8;
        qsrc[r][0] = Qh + ga; qsrc[r][1] = Ql + ga;
        ksrc[r][0] = Kh + gb; ksrc[r][1] = Kl + gb;
        qdst[r][0] = (char*)&stage[0][0][0] + c * 16;
        qdst[r][1] = (char*)&stage[1][0][0] + c * 16;
        kdst[r][0] = (char*)&stage[2][0][0] + c * 16;
        kdst[r][1] = (char*)&stage[3][0][0] + c * 16;
    }

    f32x4 acc[4][4] = {};

    for (int k0 = 0; k0 < DIM; k0 += 32) {
        #pragma unroll
        for (int r = 0; r < 2; ++r) {
            gll16(qsrc[r][0], qdst[r][0]); qsrc[r][0] += 32;
            gll16(qsrc[r][1], qdst[r][1]); qsrc[r][1] += 32;
            gll16(ksrc[r][0], kdst[r][0]); ksrc[r][0] += 32;
            gll16(ksrc[r][1], kdst[r][1]); ksrc[r][1] += 32;
        }
        __syncthreads();

        bf16x8 ah[4], al[4], bh[4], bl[4];
        #pragma unroll
        for (int m = 0; m < 4; ++m) {
            int row = wm * 64 + m * 16 + fr;
            ah[m] = *(const bf16x8*)&stage[0][row][kb * 8];
            al[m] = *(const bf16x8*)&stage[1][row][kb * 8];
        }
        #pragma unroll
        for (int n = 0; n < 4; ++n) {
            int col = wn * 64 + n * 16 + fr;
            bh[n] = *(const bf16x8*)&stage[2][col][kb * 8];
            bl[n] = *(const bf16x8*)&stage[3][col][kb * 8];
        }
        #pragma unroll
        for (int m = 0; m < 4; ++m)
            #pragma unroll
            for (int n = 0; n < 4; ++n) {
                acc[m][n] = MFMA16(ah[m], bh[n], acc[m][n], 0, 0, 0);
                acc[m][n] = MFMA16(ah[m], bl[n], acc[m][n], 0, 0, 0);
                acc[m][n] = MFMA16(al[m], bh[n], acc[m][n], 0, 0, 0);
            }
        __syncthreads();
    }

    // ---- phase A: per-row max over this block's 128 cols
    #pragma unroll
    for (int m = 0; m < 4; ++m)
        #pragma unroll
        for (int e = 0; e < 4; ++e) {
            float mx = acc[m][0][e];
            #pragma unroll
            for (int n = 1; n < 4; ++n) mx = fmaxf(mx, acc[m][n][e]);
            #pragma unroll
            for (int o = 1; o < 16; o <<= 1) mx = fmaxf(mx, __shfl_xor(mx, o));
            if (fr == 0) ps[wn][wm * 64 + m * 16 + kb * 4 + e].x = mx;
        }
    __syncthreads();
    if (t < 128) gmr[t] = fmaxf(ps[0][t].x, ps[1][t].x);
    __syncthreads();

    // ---- phase B: single exp pass -> bf16 tile (XOR-swizzled) + sumexp
    unsigned short* tile = (unsigned short*)&stage[0][0][0];   // [128][128]
    #pragma unroll
    for (int m = 0; m < 4; ++m)
        #pragma unroll
        for (int e = 0; e < 4; ++e) {
            const int rl = wm * 64 + m * 16 + kb * 4 + e;
            const float g = gmr[rl];
            const int key = kb << 1;
            float se = 0.f;
            #pragma unroll
            for (int n = 0; n < 4; ++n) {
                float ev = __expf(acc[m][n][e] - g);
                se += ev;
                const int col = wn * 64 + n * 16 + fr;
                tile[rl * 128 + (((col >> 3) ^ key) << 3) + (col & 7)] =
                    f2bf(ev);
            }
            #pragma unroll
            for (int o = 1; o < 16; o <<= 1) se += __shfl_xor(se, o);
            if (fr == 0) ps[wn][rl].y = se;
        }
    __syncthreads();
    if (t < 128)
        pstat[(size_t)(m0 + t) * 64 + nb] =
            make_float2(gmr[t], ps[0][t].y + ps[1][t].y);

    // ---- coalesced bf16 store into the packed slot
    #pragma unroll
    for (int p = 0; p < 8; ++p) {
        int c = p * 256 + t;
        int r = c >> 4, sl = c & 15;
        int slx = sl ^ (((r >> 2) & 3) << 1);
        *(int4*)&Sb[(size_t)(m0 + r) * 16384 + sbbase + sl * 8] =
            *(const int4*)((const char*)tile + (r * 16 + slx) * 16);
    }
}

// ---------------------------------------------------------------------------
// av_mfma: producer/consumer split, 512 threads.
// Waves 0-3: ZA partials = (factor * Sb) @ VT^T (MFMA + staging).
// Waves 4-7: in-place fp32 attn expansion of the step being computed.
// ---------------------------------------------------------------------------
__global__ __launch_bounds__(512, 2) void av_mfma_kernel(
    const unsigned short* __restrict__ Sb, const float2* __restrict__ pstat,
    const unsigned short* __restrict__ VT, float* __restrict__ attn,
    float* __restrict__ P0, float* __restrict__ P1,
    float* __restrict__ P2, float* __restrict__ P3)
{
    __shared__ unsigned short As[2][64][128];
    __shared__ float facsT[16][64];

    const int bid = blockIdx.x;
    const int x = bid & 7, i = bid >> 3;
    const int ks = i >> 4;
    const int rb = (i & 15) * 8 + x;
    const int r0 = rb * 64, kbase = ks * 2048, cb0 = ks * 16;
    const int t = threadIdx.x;
    const bool producer = (t < 256);
    const int tp = t & 255;
    const int lane = tp & 63, w = tp >> 6;
    const int fr = lane & 15, kb = lane >> 4;

    {
        const int row = t >> 3;
        const int sub = t & 7;
        const float2* pp = pstat + (size_t)(r0 + row) * 64 + sub * 8;
        float m = -3.0e38f, s = 0.f;
        #pragma unroll
        for (int jj = 0; jj < 8; ++jj) {
            float2 v = pp[jj];
            float nm = fmaxf(m, v.x);
            s = s * __expf(m - nm) + v.y * __expf(v.x - nm);
            m = nm;
        }
        #pragma unroll
        for (int o = 1; o < 8; o <<= 1) {
            float om = __shfl_xor(m, o);
            float os = __shfl_xor(s, o);
            float nm = fmaxf(m, om);
            s = s * __expf(m - nm) + os * __expf(om - nm);
            m = nm;
        }
        const float inv = 1.0f / s;
        #pragma unroll
        for (int jj = 0; jj < 2; ++jj) {
            int cb = sub * 2 + jj;
            float2 v = pstat[(size_t)(r0 + row) * 64 + cb0 + cb];
            facsT[cb][row] = __expf(v.x - m) * inv;
        }
    }

    const unsigned short* vb[4];
    #pragma unroll
    for (int n = 0; n < 4; ++n)
        vb[n] = VT + (size_t)(w * 64 + n * 16 + fr) * N_NODES + kbase + kb * 8;

    const unsigned short* ssrc[4];
    char* sdst[4];
    #pragma unroll
    for (int p = 0; p < 4; ++p) {
        int c = p * 256 + tp;
        int rr = c >> 4, sl = c & 15;
        int slp = sl ^ (rr & 7);
        ssrc[p] = Sb + (size_t)(r0 + rr) * 16384 + ks * 4096 + 2048 + slp * 8;
        sdst[p] = (char*)&As[0][0][0] + c * 16;
    }

    #define STAGE(BUF_) do {                                                  \
        _Pragma("unroll")                                                     \
        for (int p = 0; p < 4; ++p) {                                         \
            gll16(ssrc[p], sdst[p] + (BUF_) * 16384);                         \
            ssrc[p] += 128;                                                   \
        } } while (0)

    f32x4 acc[4][4] = {};
    const f32x4 z4 = {0.f, 0.f, 0.f, 0.f};

    if (producer) STAGE(0);
    __syncthreads();

    for (int s = 0; s < 16; ++s) {
        const int b = s & 1;
        const char* abase = (const char*)&As[b][0][0];

        if (producer) {
            if (s + 1 < 16) STAGE(b ^ 1);

            bf16x8 bb[4][4];
            #pragma unroll
            for (int ksl = 0; ksl < 4; ++ksl)
                #pragma unroll
                for (int n = 0; n < 4; ++n)
                    bb[ksl][n] = *(const bf16x8*)(vb[n] + s * 128 + ksl * 32);

            #pragma unroll
            for (int m = 0; m < 4; ++m) {
                f32x4 sacc[4];
                {
                    bf16x8 a = *(const bf16x8*)(abase + (m * 16 + fr) * 256 +
                                                ((kb ^ (fr & 7)) * 16));
                    #pragma unroll
                    for (int n = 0; n < 4; ++n)
                        sacc[n] = MFMA16(a, bb[0][n], z4, 0, 0, 0);
                }
                #pragma unroll
                for (int ksl = 1; ksl < 4; ++ksl) {
                    bf16x8 a = *(const bf16x8*)(abase + (m * 16 + fr) * 256 +
                                                (((ksl * 4 + kb) ^ (fr & 7)) * 16));
                    #pragma unroll
                    for (int n = 0; n < 4; ++n)
                        sacc[n] = MFMA16(a, bb[ksl][n], sacc[n], 0, 0, 0);
                }
                f32x4 fac = *(const f32x4*)&facsT[s][m * 16 + kb * 4];
                #pragma unroll
                for (int n = 0; n < 4; ++n)
                    acc[m][n] += fac * sacc[n];
            }
        } else {
            #pragma unroll
            for (int p = 0; p < 4; ++p) {
                int ci = p * 256 + tp;
                int rr = ci >> 4, g = ci & 15;
                const float fac = facsT[s][rr];
                int4 v = *(const int4*)(abase + (rr * 16 + (g ^ (rr & 7))) * 16);
                float* dst = attn + (size_t)(r0 + rr) * N_NODES +
                             kbase + s * 128 + g * 8;
                float4 o0, o1;
                o0.x = bf2f((unsigned short)(v.x & 0xffff)) * fac;
                o0.y = bf2f((unsigned short)((unsigned)v.x >> 16)) * fac;
                o0.z = bf2f((unsigned short)(v.y & 0xffff)) * fac;
                o0.w = bf2f((unsigned short)((unsigned)v.y >> 16)) * fac;
                o1.x = bf2f((unsigned short)(v.z & 0xffff)) * fac;
                o1.y = bf2f((unsigned short)((unsigned)v.z >> 16)) * fac;
                o1.z = bf2f((unsigned short)(v.w & 0xffff)) * fac;
                o1.w = bf2f((unsigned short)((unsigned)v.w >> 16)) * fac;
                *(float4*)dst       = o0;
                *(float4*)(dst + 4) = o1;
            }
        }
        __syncthreads();
    }
    #undef STAGE

    if (producer) {
        float* P = (ks == 0) ? P0 : (ks == 1) ? P1 : (ks == 2) ? P2 : P3;
        #pragma unroll
        for (int m = 0; m < 4; ++m)
            #pragma unroll
            for (int e = 0; e < 4; ++e) {
                int row = r0 + m * 16 + kb * 4 + e;
                #pragma unroll
                for (int n = 0; n < 4; ++n)
                    P[(size_t)row * DIM + w * 64 + n * 16 + fr] = acc[m][n][e];
            }
    }
}

// ---------------------------------------------------------------------------
// SpMM: one 64-lane wave per node, lane holds 4 features (ushort4 loads).
// ---------------------------------------------------------------------------
__global__ __launch_bounds__(256) void spmm_kernel(
    const unsigned short* __restrict__ Hb, const int* __restrict__ erow,
    const int* __restrict__ ecol, const float* __restrict__ ew,
    float* __restrict__ out, int E)
{
    const int node = blockIdx.x * 4 + (threadIdx.x >> 6);
    const int lane = threadIdx.x & 63;

    int lo = 0, hi = E;
    while (lo < hi) { int mid = (lo + hi) >> 1; if (erow[mid] < node) lo = mid + 1; else hi = mid; }
    const int beg = lo;
    hi = E;
    while (lo < hi) { int mid = (lo + hi) >> 1; if (erow[mid] < node + 1) lo = mid + 1; else hi = mid; }
    const int end = lo;

    float4 acc = make_float4(0.f, 0.f, 0.f, 0.f);
    for (int e = beg; e < end; ++e) {
        const int col = ecol[e];
        const float wgt = ew[e];
        ushort4 h = *(const ushort4*)&Hb[(size_t)col * DIM + lane * 4];
        acc.x += wgt * bf2f(h.x);
        acc.y += wgt * bf2f(h.y);
        acc.z += wgt * bf2f(h.z);
        acc.w += wgt * bf2f(h.w);
    }
    *(float4*)&out[(size_t)node * DIM + lane * 4] = acc;
}

// ---------------------------------------------------------------------------
// Y = (0.5*(P0+P1+P2+P3) + 0.5*GNN) @ Wc + bc
// ---------------------------------------------------------------------------
__global__ __launch_bounds__(256) void blend_cls_kernel(
    const float* __restrict__ p0, const float* __restrict__ p1,
    const float* __restrict__ p2, const float* __restrict__ p3,
    const float* __restrict__ gnn,
    const float* __restrict__ Wc, const float* __restrict__ bc,
    float* __restrict__ Y)
{
    const int row = blockIdx.x;
    const int t = threadIdx.x;
    __shared__ float z[DIM];
    __shared__ float part[4][NCLS];

    const size_t i = (size_t)row * DIM + t;
    z[t] = 0.5f * (p0[i] + p1[i] + p2[i] + p3[i] + gnn[i]);
    __syncthreads();

    if (t < 160) {
        const int c = t % NCLS, q = t / NCLS;
        float acc = 0.0f;
        #pragma unroll 4
        for (int d = q * 64; d < q * 64 + 64; ++d)
            acc += z[d] * Wc[d * NCLS + c];
        part[q][c] = acc;
    }
    __syncthreads();
    if (t < NCLS)
        Y[(size_t)row * NCLS + t] =
            part[0][t] + part[1][t] + part[2][t] + part[3][t] + bc[t];
}

// ---------------------------------------------------------------------------
extern "C" void kernel_launch(void* const* d_in, const int* in_sizes, int n_in,
                              void* d_out, int out_size, void* d_ws, size_t ws_size,
                              hipStream_t stream)
{
    const float* X     = (const float*)d_in[0];
    const int*   erow  = (const int*)d_in[1];
    const int*   ecol  = (const int*)d_in[2];
    const float* ew    = (const float*)d_in[3];
    const float* W_emb = (const float*)d_in[4];
    const float* b_emb = (const float*)d_in[5];
    const float* W_q   = (const float*)d_in[6];
    const float* b_q   = (const float*)d_in[7];
    const float* W_k   = (const float*)d_in[8];
    const float* b_k   = (const float*)d_in[9];
    const float* W_v   = (const float*)d_in[10];
    const float* b_v   = (const float*)d_in[11];
    const float* W_g   = (const float*)d_in[12];
    const float* b_g   = (const float*)d_in[13];
    const float* W_c   = (const float*)d_in[14];
    const float* b_c   = (const float*)d_in[15];
    const int E = in_sizes[1];

    float* Y    = (float*)d_out;
    float* Sc   = Y + (size_t)N_NODES * NCLS;
    unsigned short* Sb = (unsigned short*)Sc;

    const size_t ND = (size_t)N_NODES * DIM;
    float* R0 = (float*)d_ws;
    float* R1 = R0 + ND;
    float* R2 = R1 + ND;
    float* R3 = R2 + ND;
    float* R4 = R3 + ND;
    float* R5 = R4 + ND;
    float* R6 = R5 + ND;

    unsigned short* Xh = (unsigned short*)R0;
    unsigned short* Xl = (unsigned short*)R1;
    unsigned short* Wt = (unsigned short*)R2;
    unsigned short* WembTh = Wt;
    unsigned short* WembTl = Wt + 256 * 512;
    unsigned short* WqTh = WembTl + 256 * 512;
    unsigned short* WqTl = WqTh + 256 * 256;
    unsigned short* WkTh = WqTl + 256 * 256;
    unsigned short* WkTl = WkTh + 256 * 256;
    unsigned short* WvTh = WkTl + 256 * 256;
    unsigned short* WvTl = WvTh + 256 * 256;
    unsigned short* WgTh = WvTl + 256 * 256;
    unsigned short* WgTl = WgTh + 256 * 256;
    unsigned short* Z0h = (unsigned short*)R3;
    unsigned short* Z0l = Z0h + ND;
    float* Qf = R4;
    float* Kf = R5;
    float* Vf = R6;
    unsigned short* Hb = (unsigned short*)R0;
    unsigned short* Qh = (unsigned short*)R1;
    unsigned short* Ql = Qh + ND;
    unsigned short* Kh = (unsigned short*)R2;
    unsigned short* Kl = Kh + ND;
    unsigned short* VT = (unsigned short*)(R0 + ND / 2);
    float2* pstat = (float2*)R4;
    float* P0 = R6;
    float* P1 = R3;
    float* P2 = R5;
    float* P3 = R1;
    float* GNN = R2;

    // 1. X -> hi/lo bf16
    split_kernel<<<(N_NODES * F_IN) / 1024, 256, 0, stream>>>(X, Xh, Xl);

    // 2. weight transposes
    wtrans_kernel<<<dim3(F_IN / 64, DIM / 64), 256, 0, stream>>>(
        W_emb, WembTh, WembTl, F_IN, DIM);
    Wt4Args wa;
    wa.W[0] = W_q; wa.Th[0] = WqTh; wa.Tl[0] = WqTl;
    wa.W[1] = W_k; wa.Th[1] = WkTh; wa.Tl[1] = WkTl;
    wa.W[2] = W_v; wa.Th[2] = WvTh; wa.Tl[2] = WvTl;
    wa.W[3] = W_g; wa.Th[3] = WgTh; wa.Tl[3] = WgTl;
    wtrans4_kernel<<<dim3(DIM / 64, DIM / 64, 4), 256, 0, stream>>>(wa);

    // 3. Z0 = X @ W_emb + b
    mfma_gemm3_kernel<F_IN, 2, 64><<<dim3(2, N_NODES / 64), 256, 0, stream>>>(
        Xh, Xl, WembTh, WembTl, b_emb, Z0h, Z0l);

    // 4. projections
    Proj4Args pa;
    pa.Bh[0] = WqTh; pa.Bl[0] = WqTl; pa.bias[0] = b_q; pa.C[0] = Qf;
    pa.Bh[1] = WkTh; pa.Bl[1] = WkTl; pa.bias[1] = b_k; pa.C[1] = Kf;
    pa.Bh[2] = WvTh; pa.Bl[2] = WvTl; pa.bias[2] = b_v; pa.C[2] = Vf;
    pa.Bh[3] = WgTh; pa.Bl[3] = WgTl; pa.bias[3] = b_g; pa.C[3] = Hb;
    proj4_kernel<<<dim3(2, N_NODES / 128, 4), 256, 0, stream>>>(Z0h, Z0l, pa);

    // 5. LN + split
    ln_split2_kernel<<<dim3(N_NODES, 2), 256, 0, stream>>>(
        Qf, Kf, Qh, Ql, Kh, Kl);

    // 6. V -> VT
    vtrans_kernel<<<dim3(N_NODES / 64, DIM / 64), 256, 0, stream>>>(Vf, VT);

    // 7. Sb + pstat (128x128 tiles, 4 waves — verified config)
    qkt_kernel<<<4096, 256, 0, stream>>>(Qh, Ql, Kh, Kl, Sb, pstat);

    // 8. ZA partials + factors + in-place attn expansion
    av_mfma_kernel<<<512, 512, 0, stream>>>(
        Sb, pstat, VT, Sc, P0, P1, P2, P3);

    // 9. GNN branch
    spmm_kernel<<<N_NODES / 4, 256, 0, stream>>>(Hb, erow, ecol, ew, GNN, E);

    // 10. blend + classifier
    blend_cls_kernel<<<N_NODES, 256, 0, stream>>>(
        P0, P1, P2, P3, GNN, W_c, b_c, Y);
}